// Round 3
// baseline (767.772 us; speedup 1.0000x reference)
//
#include <hip/hip_runtime.h>
#include <stdint.h>

#define NTOK  262144
#define HD    256

typedef unsigned short u16;
typedef unsigned int   u32;
typedef __attribute__((ext_vector_type(8))) short bfrag;   // 8 bf16 (4 VGPRs)
typedef __attribute__((ext_vector_type(4))) float facc;    // MFMA C/D
typedef __attribute__((ext_vector_type(4))) float f32x4v;
typedef __attribute__((ext_vector_type(2))) unsigned int u32x2;

// ---- ws layout (bytes) ----
// w1t: bf16 fragment-major [s=kc*2+h2 (8)][nt (16)][cl (16)][q (4)][8]  = 131072 B
// wet: bf16 fragment-major [(e*8+s) (32)][c (256)][q (4)][8]            = 524288 B
#define WS_W1T   0
#define WS_WET   131072
#define WS_WCOMB 655360     // f32 [k=256][e=4]
#define WS_BCOMB 659456     // f32 [4]
#define WS_FLAG  659472     // u64 prep-done magic
#define WS_HBUF  660480ull                          // bf16 h^T-layout [tok][256]
#define HBUF_BYTES 134217728ull
#define WS_GATE  (WS_HBUF + HBUF_BYTES)             // f32 [NTOK]
#define WS_EIDX  (WS_GATE + 1048576ull)             // i32 [NTOK]
#define WS_SPLIT_END (WS_EIDX + 1048576ull)         // 136,975,360 B
#define PREP_MAGIC 0x9e3779b97f4a7c15ull

static __device__ __forceinline__ u16 f2bf(float f) {  // fp32 -> bf16 RNE
  union { float f; uint32_t u; } v; v.f = f;
  uint32_t r = v.u + 0x7FFFu + ((v.u >> 16) & 1u);
  return (u16)(r >> 16);
}

// ---------- single prep kernel: swizzle W1/We to fragment layout + Wcomb ----------
__global__ __launch_bounds__(256)
void prep_all(const float* __restrict__ W1, const float* __restrict__ b1,
              const float* __restrict__ Wg, const float* __restrict__ We,
              u16* __restrict__ w1t, u16* __restrict__ wet,
              float* __restrict__ wcomb, float* __restrict__ bcomb,
              const unsigned long long* __restrict__ flag) {
  if (*flag == PREP_MAGIC) return;
  const int b = blockIdx.x, t = threadIdx.x;
  if (b < 160) {
    int id = b * 256 + t;                 // one bf16x8 fragment per thread
    if (id < 8192) {
      int q = id & 3, cl = (id >> 2) & 15, nt = (id >> 6) & 15;
      int h2 = (id >> 10) & 1, kc = id >> 11;
      int k0 = kc * 64 + h2 * 32 + q * 8, c = nt * 16 + cl;
      bfrag v;
#pragma unroll
      for (int j = 0; j < 8; ++j) v[j] = (short)f2bf(W1[(size_t)(k0 + j) * 256 + c]);
      *(bfrag*)(w1t + (size_t)id * 8) = v;
    } else {
      int s = id - 8192;
      int q = s & 3, c = (s >> 2) & 255, h2 = (s >> 10) & 1;
      int kc = (s >> 11) & 3, e = s >> 13;
      int k0 = kc * 64 + h2 * 32 + q * 8;
      const float* Wep = We + (size_t)e * 65536;
      bfrag v;
#pragma unroll
      for (int j = 0; j < 8; ++j) v[j] = (short)f2bf(Wep[(size_t)(k0 + j) * 256 + c]);
      *(bfrag*)(wet + (size_t)s * 8) = v;
    }
  } else {
    // Wcomb = W1@Wg, bcomb = b1@Wg in fp64, one wave per output element
    int o = (b - 160) * 4 + (t >> 6);
    int l = t & 63;
    if (o < 1024) {
      int k = o >> 2, e = o & 3;
      double acc = 0.0;
#pragma unroll
      for (int i = 0; i < 4; ++i) {
        int m = l + 64 * i;
        acc += (double)W1[k * 256 + m] * (double)Wg[m * 4 + e];
      }
#pragma unroll
      for (int m = 32; m >= 1; m >>= 1) acc += __shfl_xor(acc, m, 64);
      if (l == 0) wcomb[o] = (float)acc;
    } else if (o < 1028) {
      int e = o - 1024;
      double acc = 0.0;
#pragma unroll
      for (int i = 0; i < 4; ++i) {
        int m = l + 64 * i;
        acc += (double)b1[m] * (double)Wg[m * 4 + e];
      }
#pragma unroll
      for (int m = 32; m >= 1; m >>= 1) acc += __shfl_xor(acc, m, 64);
      if (l == 0) bcomb[e] = (float)acc;
    }
  }
}

// ---------- kernel A: fused gating + h, wave-autonomous, ZERO LDS / barriers ----
// Swapped-operand MFMA: D = (W1^T)(x^T) = h^T. Thread (cl,q) ends with
// h[tok=cl][hcol=nt*16+q*4+r] -> 4 consecutive hcols per acc block -> b64 stores
// in exactly the layout kernel B consumes as B-fragments.
__global__ __launch_bounds__(256, 4)
void gate_h(const float* __restrict__ x,
            const u16* __restrict__ w1t,
            const float* __restrict__ wcomb, const float* __restrict__ bcomb,
            const float* __restrict__ b1,
            u16* __restrict__ hbuf, float* __restrict__ gbuf, int* __restrict__ ebuf,
            unsigned long long* __restrict__ flag) {
  const int t = threadIdx.x, lane = t & 63, w = t >> 6;
  const int cl = lane & 15, q = lane >> 4;
  const int tok = blockIdx.x * 64 + w * 16 + cl;
  if (blockIdx.x == 0 && t == 0) *flag = PREP_MAGIC;  // prep done (stream-ordered)

  const float* xr = x + (size_t)tok * HD;
  facc acc[16];
#pragma unroll
  for (int nt = 0; nt < 16; ++nt) acc[nt] = (facc){0.f, 0.f, 0.f, 0.f};
  double la0 = 0.0, la1 = 0.0, la2 = 0.0, la3 = 0.0;

#pragma unroll
  for (int s = 0; s < 8; ++s) {
    const int kk = s * 32 + q * 8;
    f32x4v xa = *(const f32x4v*)(xr + kk);
    f32x4v xb = *(const f32x4v*)(xr + kk + 4);
    // logits partials over this lane's k-slice (fp64, flip-safe reassociation)
    const float* wp = wcomb + (size_t)kk * 4;
#pragma unroll
    for (int j = 0; j < 4; ++j) {
      f32x4v wv = *(const f32x4v*)(wp + j * 4);
      double xj = (double)xa[j];
      la0 += xj * (double)wv.x; la1 += xj * (double)wv.y;
      la2 += xj * (double)wv.z; la3 += xj * (double)wv.w;
    }
#pragma unroll
    for (int j = 0; j < 4; ++j) {
      f32x4v wv = *(const f32x4v*)(wp + 16 + j * 4);
      double xj = (double)xb[j];
      la0 += xj * (double)wv.x; la1 += xj * (double)wv.y;
      la2 += xj * (double)wv.z; la3 += xj * (double)wv.w;
    }
    bfrag xf;
    xf[0] = (short)f2bf(xa.x); xf[1] = (short)f2bf(xa.y);
    xf[2] = (short)f2bf(xa.z); xf[3] = (short)f2bf(xa.w);
    xf[4] = (short)f2bf(xb.x); xf[5] = (short)f2bf(xb.y);
    xf[6] = (short)f2bf(xb.z); xf[7] = (short)f2bf(xb.w);
    const u16* wp1 = w1t + (size_t)(s * 16) * 512 + (size_t)(cl * 4 + q) * 8;
#pragma unroll
    for (int nt = 0; nt < 16; ++nt) {
      bfrag wf = *(const bfrag*)(wp1 + (size_t)nt * 512);
      acc[nt] = __builtin_amdgcn_mfma_f32_16x16x32_bf16(wf, xf, acc[nt], 0, 0, 0);
    }
  }

  // reduce logits across the 4 q-lanes of this token (fp64 -> flip-safe)
  la0 += __shfl_xor(la0, 16, 64); la0 += __shfl_xor(la0, 32, 64);
  la1 += __shfl_xor(la1, 16, 64); la1 += __shfl_xor(la1, 32, 64);
  la2 += __shfl_xor(la2, 16, 64); la2 += __shfl_xor(la2, 32, 64);
  la3 += __shfl_xor(la3, 16, 64); la3 += __shfl_xor(la3, 32, 64);
  float l0 = (float)(la0 + (double)bcomb[0]);
  float l1 = (float)(la1 + (double)bcomb[1]);
  float l2 = (float)(la2 + (double)bcomb[2]);
  float l3 = (float)(la3 + (double)bcomb[3]);
  // softmax / argmax — formula identical to verified kernel
  float m = fmaxf(fmaxf(l0, l1), fmaxf(l2, l3));
  float ssum = __expf(l0 - m) + __expf(l1 - m) + __expf(l2 - m) + __expf(l3 - m);
  int e = 0; float bl = l0;
  if (l1 > bl) { bl = l1; e = 1; }
  if (l2 > bl) { bl = l2; e = 2; }
  if (l3 > bl) { bl = l3; e = 3; }
  if (q == 0) { gbuf[tok] = 1.0f / ssum; ebuf[tok] = e; }

  // h^T epilogue: +b1, bf16 RNE, b64 stores (4 consecutive hcols)
  u16* hb = hbuf + (size_t)tok * HD;
#pragma unroll
  for (int nt = 0; nt < 16; ++nt) {
    const int c0 = nt * 16 + q * 4;
    f32x4v bv = *(const f32x4v*)(b1 + c0);
    float v0 = acc[nt][0] + bv.x, v1 = acc[nt][1] + bv.y;
    float v2 = acc[nt][2] + bv.z, v3 = acc[nt][3] + bv.w;
    u32x2 pk;
    pk.x = (u32)f2bf(v0) | ((u32)f2bf(v1) << 16);
    pk.y = (u32)f2bf(v2) | ((u32)f2bf(v3) << 16);
    *(u32x2*)(hb + c0) = pk;
  }
}

// ---------- kernel B: grouped expert GEMM, tiny LDS, 32 waves/CU ------------
#define BM2 256
__global__ __launch_bounds__(512, 4)
void expert_gemm(const u16* __restrict__ hbuf, const u16* __restrict__ wet,
                 const float* __restrict__ gbuf, const int* __restrict__ ebuf,
                 const float* __restrict__ be, float* __restrict__ out) {
  __shared__ float gate_s[BM2];
  __shared__ int   perm_s[BM2];
  __shared__ int   eidx_s[BM2];
  __shared__ int   pos_s[BM2];
  __shared__ int   cnt_s[4];
  __shared__ int   base_s[4];

  const int t = threadIdx.x, lane = t & 63, w = t >> 6;
  const int cl = lane & 15, q = lane >> 4;
  const int tokbase = blockIdx.x * BM2;

  if (t < 4) cnt_s[t] = 0;
  __syncthreads();
  if (t < BM2) {
    gate_s[t] = gbuf[tokbase + t];
    int e = ebuf[tokbase + t];
    eidx_s[t] = e;
    pos_s[t]  = atomicAdd(&cnt_s[e], 1);
  }
  __syncthreads();
  if (t == 0) {
    int b = 0;
#pragma unroll
    for (int e = 0; e < 4; ++e) { base_s[e] = b; b += cnt_s[e]; }
  }
  __syncthreads();
  if (t < BM2) perm_s[base_s[eidx_s[t]] + pos_s[t]] = t;
  __syncthreads();

  const int wcol = w * 32;                 // this wave's 32 outcols (2 tiles)
  for (int e = 0; e < 4; ++e) {
    const int cnt = cnt_s[e];              // block-uniform
    if (cnt == 0) continue;
    const int ng   = (cnt + 15) >> 4;
    const int base = base_s[e];
    for (int g = 0; g < ng; ++g) {
      const int  rowi  = g * 16 + cl;
      const bool valid = rowi < cnt;
      const int  tl    = perm_s[base + (valid ? rowi : 0)];
      const u16* hp = hbuf + (size_t)(tokbase + tl) * HD + q * 8;
      bfrag hf[8];
#pragma unroll
      for (int s = 0; s < 8; ++s) hf[s] = *(const bfrag*)(hp + s * 32);
      if (!valid) {
#pragma unroll
        for (int s = 0; s < 8; ++s) { bfrag z = {0,0,0,0,0,0,0,0}; hf[s] = z; }
      }
      facc a0 = (facc){0.f, 0.f, 0.f, 0.f};
      facc a1 = (facc){0.f, 0.f, 0.f, 0.f};
#pragma unroll
      for (int s = 0; s < 8; ++s) {
        const u16* wp = wet + (size_t)(e * 8 + s) * 8192
                            + (size_t)(w * 2) * 512 + (size_t)(cl * 4 + q) * 8;
        bfrag wf0 = *(const bfrag*)(wp);
        bfrag wf1 = *(const bfrag*)(wp + 512);
        a0 = __builtin_amdgcn_mfma_f32_16x16x32_bf16(wf0, hf[s], a0, 0, 0, 0);
        a1 = __builtin_amdgcn_mfma_f32_16x16x32_bf16(wf1, hf[s], a1, 0, 0, 0);
      }
      if (valid) {
        const int   tok  = tokbase + tl;
        const float gate = gate_s[tl];
        {
          const int c0 = wcol + q * 4;
          f32x4v bev = *(const f32x4v*)(be + e * 256 + c0);
          f32x4v o;
          o.x = gate * (a0[0] + bev.x); o.y = gate * (a0[1] + bev.y);
          o.z = gate * (a0[2] + bev.z); o.w = gate * (a0[3] + bev.w);
          *(f32x4v*)(out + (size_t)tok * HD + c0) = o;
        }
        {
          const int c0 = wcol + 16 + q * 4;
          f32x4v bev = *(const f32x4v*)(be + e * 256 + c0);
          f32x4v o;
          o.x = gate * (a1[0] + bev.x); o.y = gate * (a1[1] + bev.y);
          o.z = gate * (a1[2] + bev.z); o.w = gate * (a1[3] + bev.w);
          *(f32x4v*)(out + (size_t)tok * HD + c0) = o;
        }
      }
    }
  }
}

// ---------- fallback: R2-verified fused kernel (used when ws is too small) ----
#define BM 128
#define NBLK (NTOK / BM)
__global__ __launch_bounds__(512, 4)
void moe_fused(const float* __restrict__ x,
               const u16* __restrict__ w1t, const u16* __restrict__ wet,
               const float* __restrict__ wcomb, const float* __restrict__ bcomb,
               const float* __restrict__ b1, const float* __restrict__ be,
               float* __restrict__ out, unsigned long long* __restrict__ flag) {
  __shared__ u16   hs[BM][264];
  __shared__ float b1s[256];
  __shared__ float logits_s[BM][4];
  __shared__ float gate_s[BM];
  __shared__ int   pos_s[BM];
  __shared__ int   eidx_s[BM];
  __shared__ int   perm_s[BM];
  __shared__ int   cnt_s[4];
  __shared__ int   base_s[4];

  const int t    = threadIdx.x;
  const int lane = t & 63;
  const int w    = t >> 6;
  const int cl   = lane & 15;
  const int q    = lane >> 4;
  const int tokbase = blockIdx.x * BM;

  if (blockIdx.x == 0 && t == 0) *flag = PREP_MAGIC;

  float* wcT = (float*)&hs[0][0];

  if (t < 256) b1s[t] = b1[t];
  if (t < 4) cnt_s[t] = 0;
#pragma unroll
  for (int i = 0; i < 2; ++i) {
    int idx = i * 512 + t;
    wcT[(idx & 3) * 260 + (idx >> 2)] = wcomb[idx];
  }
  __syncthreads();

  {
    const int tok = t >> 2, e = t & 3;
    const float* xr = x + (size_t)(tokbase + tok) * HD;
    const float* wc = wcT + e * 260;
    double a0 = 0.0, a1 = 0.0, a2 = 0.0, a3 = 0.0;
    for (int k = 0; k < HD; k += 32) {
      f32x4v xv[8];
#pragma unroll
      for (int j = 0; j < 8; ++j) xv[j] = *(const f32x4v*)(xr + k + 4 * j);
#pragma unroll
      for (int j = 0; j < 8; ++j) {
        f32x4v wv = *(const f32x4v*)(wc + k + 4 * j);
        a0 += (double)xv[j].x * (double)wv.x;
        a1 += (double)xv[j].y * (double)wv.y;
        a2 += (double)xv[j].z * (double)wv.z;
        a3 += (double)xv[j].w * (double)wv.w;
      }
    }
    logits_s[tok][e] = (float)(((a0 + a1) + (a2 + a3)) + (double)bcomb[e]);
  }
  __syncthreads();

  if (t < BM) {
    float l0 = logits_s[t][0], l1 = logits_s[t][1];
    float l2 = logits_s[t][2], l3 = logits_s[t][3];
    float m = fmaxf(fmaxf(l0, l1), fmaxf(l2, l3));
    float s = __expf(l0 - m) + __expf(l1 - m) + __expf(l2 - m) + __expf(l3 - m);
    int e = 0; float bl = l0;
    if (l1 > bl) { bl = l1; e = 1; }
    if (l2 > bl) { bl = l2; e = 2; }
    if (l3 > bl) { bl = l3; e = 3; }
    gate_s[t] = 1.0f / s;
    eidx_s[t] = e;
    pos_s[t]  = atomicAdd(&cnt_s[e], 1);
  }
  __syncthreads();
  if (t == 0) {
    int b = 0;
#pragma unroll
    for (int e = 0; e < 4; ++e) { base_s[e] = b; b += cnt_s[e]; }
  }
  __syncthreads();
  if (t < BM) perm_s[base_s[eidx_s[t]] + pos_s[t]] = t;

  const int rw = w >> 1, wc2 = w & 1;
  facc acc1[2][8];
#pragma unroll
  for (int m = 0; m < 2; ++m)
#pragma unroll
    for (int nt = 0; nt < 8; ++nt) acc1[m][nt] = (facc){0.f, 0.f, 0.f, 0.f};

  const float* xrow0 = x + (size_t)(tokbase + rw * 32 + cl) * HD;
  const float* xrow1 = xrow0 + 16 * HD;

#pragma unroll
  for (int kc = 0; kc < 4; ++kc) {
#pragma unroll
    for (int h2 = 0; h2 < 2; ++h2) {
      const int k0 = kc * 64 + h2 * 32 + q * 8;
      f32x4v xa0 = *(const f32x4v*)(xrow0 + k0);
      f32x4v xb0 = *(const f32x4v*)(xrow0 + k0 + 4);
      f32x4v xa1 = *(const f32x4v*)(xrow1 + k0);
      f32x4v xb1 = *(const f32x4v*)(xrow1 + k0 + 4);
      bfrag a0, a1;
      a0[0] = (short)f2bf(xa0.x); a0[1] = (short)f2bf(xa0.y);
      a0[2] = (short)f2bf(xa0.z); a0[3] = (short)f2bf(xa0.w);
      a0[4] = (short)f2bf(xb0.x); a0[5] = (short)f2bf(xb0.y);
      a0[6] = (short)f2bf(xb0.z); a0[7] = (short)f2bf(xb0.w);
      a1[0] = (short)f2bf(xa1.x); a1[1] = (short)f2bf(xa1.y);
      a1[2] = (short)f2bf(xa1.z); a1[3] = (short)f2bf(xa1.w);
      a1[4] = (short)f2bf(xb1.x); a1[5] = (short)f2bf(xb1.y);
      a1[6] = (short)f2bf(xb1.z); a1[7] = (short)f2bf(xb1.w);
      const u16* bp = w1t + (size_t)(kc * 2 + h2) * 8192
                          + (size_t)(wc2 * 8) * 512 + (cl * 4 + q) * 8;
#pragma unroll
      for (int nt = 0; nt < 8; ++nt) {
        bfrag bfr = *(const bfrag*)(bp + nt * 512);
        acc1[0][nt] = __builtin_amdgcn_mfma_f32_16x16x32_bf16(a0, bfr, acc1[0][nt], 0, 0, 0);
        acc1[1][nt] = __builtin_amdgcn_mfma_f32_16x16x32_bf16(a1, bfr, acc1[1][nt], 0, 0, 0);
      }
    }
  }
#pragma unroll
  for (int m = 0; m < 2; ++m)
#pragma unroll
    for (int nt = 0; nt < 8; ++nt) {
      const int c = wc2 * 128 + nt * 16 + cl;
      const float bb = b1s[c];
#pragma unroll
      for (int r = 0; r < 4; ++r)
        hs[rw * 32 + m * 16 + q * 4 + r][c] = f2bf(acc1[m][nt][r] + bb);
    }
  __syncthreads();

  for (int e = 0; e < 4; ++e) {
    const int cnt = cnt_s[e];
    if (cnt == 0) continue;
    const int ng   = (cnt + 15) >> 4;
    const int base = base_s[e];

    int  prow_r[8];
    bool val_r[8];
#pragma unroll
    for (int g = 0; g < 8; ++g) {
      const int rowi = g * 16 + cl;
      const bool v = rowi < cnt;
      val_r[g]  = v;
      prow_r[g] = perm_s[base + (v ? rowi : 0)];
    }

    facc acc2[8][2];
#pragma unroll
    for (int g = 0; g < 8; ++g) {
      acc2[g][0] = (facc){0.f, 0.f, 0.f, 0.f};
      acc2[g][1] = (facc){0.f, 0.f, 0.f, 0.f};
    }

#pragma unroll
    for (int kc = 0; kc < 4; ++kc) {
#pragma unroll
      for (int h2 = 0; h2 < 2; ++h2) {
        const int k0 = kc * 64 + h2 * 32 + q * 8;
        const u16* bp = wet + (size_t)((e * 4 + kc) * 2 + h2) * 8192
                            + (size_t)(w * 2) * 512 + (cl * 4 + q) * 8;
        bfrag bf0 = *(const bfrag*)(bp);
        bfrag bf1 = *(const bfrag*)(bp + 512);
#pragma unroll
        for (int g = 0; g < 8; ++g) {
          if (g < ng) {
            bfrag a = *(const bfrag*)&hs[prow_r[g]][k0];
            if (!val_r[g]) { bfrag z = {0,0,0,0,0,0,0,0}; a = z; }
            acc2[g][0] = __builtin_amdgcn_mfma_f32_16x16x32_bf16(a, bf0, acc2[g][0], 0, 0, 0);
            acc2[g][1] = __builtin_amdgcn_mfma_f32_16x16x32_bf16(a, bf1, acc2[g][1], 0, 0, 0);
          }
        }
      }
    }
#pragma unroll
    for (int n4 = 0; n4 < 2; ++n4) {
      const int c = w * 32 + n4 * 16 + cl;
      const float bev = be[e * 256 + c];
#pragma unroll
      for (int g = 0; g < 8; ++g) {
        if (g < ng) {
#pragma unroll
          for (int r = 0; r < 4; ++r) {
            const int rowi = g * 16 + q * 4 + r;
            if (rowi < cnt) {
              const int tok = perm_s[base + rowi];
              out[(size_t)(tokbase + tok) * HD + c] = gate_s[tok] * (acc2[g][n4][r] + bev);
            }
          }
        }
      }
    }
  }
}

extern "C" void kernel_launch(void* const* d_in, const int* in_sizes, int n_in,
                              void* d_out, int out_size, void* d_ws, size_t ws_size,
                              hipStream_t stream) {
  const float* x  = (const float*)d_in[0];
  const float* W1 = (const float*)d_in[1];
  const float* b1 = (const float*)d_in[2];
  const float* Wg = (const float*)d_in[3];
  const float* We = (const float*)d_in[4];
  const float* be = (const float*)d_in[5];
  float* out = (float*)d_out;

  char* ws = (char*)d_ws;
  u16*   w1t   = (u16*)(ws + WS_W1T);
  u16*   wet   = (u16*)(ws + WS_WET);
  float* wcomb = (float*)(ws + WS_WCOMB);
  float* bcomb = (float*)(ws + WS_BCOMB);
  unsigned long long* flag = (unsigned long long*)(ws + WS_FLAG);

  prep_all<<<417, 256, 0, stream>>>(W1, b1, Wg, We, w1t, wet, wcomb, bcomb, flag);

  if (ws_size >= WS_SPLIT_END) {
    u16*   hbuf = (u16*)(ws + WS_HBUF);
    float* gbuf = (float*)(ws + WS_GATE);
    int*   ebuf = (int*)(ws + WS_EIDX);
    gate_h<<<NTOK / 64, 256, 0, stream>>>(x, w1t, wcomb, bcomb, b1,
                                          hbuf, gbuf, ebuf, flag);
    expert_gemm<<<NTOK / BM2, 512, 0, stream>>>(hbuf, wet, gbuf, ebuf, be, out);
  } else {
    moe_fused<<<NBLK, 512, 0, stream>>>(x, w1t, wet, wcomb, bcomb, b1, be, out, flag);
  }
}

// Round 4
// 667.659 us; speedup vs baseline: 1.1499x; 1.1499x over previous
//
#include <hip/hip_runtime.h>
#include <stdint.h>

#define NTOK  262144
#define HD    256
#define BM    256
#define NBLK  (NTOK / BM)   // 1024

typedef unsigned short u16;
typedef __attribute__((ext_vector_type(8))) short bfrag;   // 8 bf16 (4 VGPRs)
typedef __attribute__((ext_vector_type(4))) float facc;    // MFMA C/D
typedef __attribute__((ext_vector_type(4))) float f32x4v;

// ---- ws layout (bytes) ----
// w1t: bf16 fragment-major [s=kc*2+h2 (8)][nt (16)][cl (16)][q (4)][8]  = 131072 B
// wet: bf16 fragment-major [(e*8+s) (32)][c (256)][q (4)][8]            = 524288 B
#define WS_W1T   0
#define WS_WET   131072
#define WS_WCOMB 655360     // f32 [k=256][e=4]
#define WS_BCOMB 659456     // f32 [4]
#define WS_FLAG  659472     // u64 prep-done magic
#define PREP_MAGIC 0x9e3779b97f4a7c15ull

static __device__ __forceinline__ u16 f2bf(float f) {  // fp32 -> bf16 RNE
  union { float f; uint32_t u; } v; v.f = f;
  uint32_t r = v.u + 0x7FFFu + ((v.u >> 16) & 1u);
  return (u16)(r >> 16);
}

// ---------- single prep kernel: swizzle W1/We to fragment layout + Wcomb ----------
__global__ __launch_bounds__(256)
void prep_all(const float* __restrict__ W1, const float* __restrict__ b1,
              const float* __restrict__ Wg, const float* __restrict__ We,
              u16* __restrict__ w1t, u16* __restrict__ wet,
              float* __restrict__ wcomb, float* __restrict__ bcomb,
              const unsigned long long* __restrict__ flag) {
  if (*flag == PREP_MAGIC) return;
  const int b = blockIdx.x, t = threadIdx.x;
  if (b < 160) {
    int id = b * 256 + t;                 // one bf16x8 fragment per thread
    if (id < 8192) {
      int q = id & 3, cl = (id >> 2) & 15, nt = (id >> 6) & 15;
      int h2 = (id >> 10) & 1, kc = id >> 11;
      int k0 = kc * 64 + h2 * 32 + q * 8, c = nt * 16 + cl;
      bfrag v;
#pragma unroll
      for (int j = 0; j < 8; ++j) v[j] = (short)f2bf(W1[(size_t)(k0 + j) * 256 + c]);
      *(bfrag*)(w1t + (size_t)id * 8) = v;
    } else {
      int s = id - 8192;
      int q = s & 3, c = (s >> 2) & 255, h2 = (s >> 10) & 1;
      int kc = (s >> 11) & 3, e = s >> 13;
      int k0 = kc * 64 + h2 * 32 + q * 8;
      const float* Wep = We + (size_t)e * 65536;
      bfrag v;
#pragma unroll
      for (int j = 0; j < 8; ++j) v[j] = (short)f2bf(Wep[(size_t)(k0 + j) * 256 + c]);
      *(bfrag*)(wet + (size_t)s * 8) = v;
    }
  } else {
    // Wcomb = W1@Wg, bcomb = b1@Wg in fp64, one wave per output element
    int o = (b - 160) * 4 + (t >> 6);
    int l = t & 63;
    if (o < 1024) {
      int k = o >> 2, e = o & 3;
      double acc = 0.0;
#pragma unroll
      for (int i = 0; i < 4; ++i) {
        int m = l + 64 * i;
        acc += (double)W1[k * 256 + m] * (double)Wg[m * 4 + e];
      }
#pragma unroll
      for (int m = 32; m >= 1; m >>= 1) acc += __shfl_xor(acc, m, 64);
      if (l == 0) wcomb[o] = (float)acc;
    } else if (o < 1028) {
      int e = o - 1024;
      double acc = 0.0;
#pragma unroll
      for (int i = 0; i < 4; ++i) {
        int m = l + 64 * i;
        acc += (double)b1[m] * (double)Wg[m * 4 + e];
      }
#pragma unroll
      for (int m = 32; m >= 1; m >>= 1) acc += __shfl_xor(acc, m, 64);
      if (l == 0) bcomb[e] = (float)acc;
    }
  }
}

// ---------- fused MoE kernel: BM=256, 16 waves, weights direct L2->register ----------
__global__ __launch_bounds__(1024, 4)
void moe_fused(const float* __restrict__ x,
               const u16* __restrict__ w1t, const u16* __restrict__ wet,
               const float* __restrict__ wcomb, const float* __restrict__ bcomb,
               const float* __restrict__ b1, const float* __restrict__ be,
               float* __restrict__ out, unsigned long long* __restrict__ flag) {
  __shared__ u16   hs[BM][264];          // h tile bf16, +8 pad (135168 B); wcT aliased
  __shared__ float b1s[256];
  __shared__ float logits_s[BM][4];
  __shared__ float gate_s[BM];
  __shared__ int   pos_s[BM];
  __shared__ int   eidx_s[BM];
  __shared__ int   perm_s[BM];
  __shared__ int   cnt_s[4];
  __shared__ int   base_s[4];
  // total LDS ~141 KB -> 1 block/CU, 16 waves/CU (50%)

  const int t    = threadIdx.x;          // 0..1023
  const int lane = t & 63;
  const int w    = t >> 6;               // 0..15
  const int cl   = lane & 15;
  const int q    = lane >> 4;
  const int tokbase = blockIdx.x * BM;

  if (blockIdx.x == 0 && t == 0) *flag = PREP_MAGIC;  // preps done (stream-ordered)

  float* wcT = (float*)&hs[0][0];        // [4][260] f32, alias (dead before hs write)

  // ---- init small LDS ----
  if (t < 256) b1s[t] = b1[t];
  if (t < 4) cnt_s[t] = 0;
  wcT[(t & 3) * 260 + (t >> 2)] = wcomb[t];   // 1024 elements, one per thread
  __syncthreads();

  // ---- logits = x @ Wcomb + bcomb, fp64 accumulation (flip-proof) ----
  // Batched loads (8 in flight) — FMA order identical to verified kernel.
  {
    const int tok = t >> 2, e = t & 3;
    const float* xr = x + (size_t)(tokbase + tok) * HD;
    const float* wc = wcT + e * 260;
    double a0 = 0.0, a1 = 0.0, a2 = 0.0, a3 = 0.0;
    for (int k = 0; k < HD; k += 32) {
      f32x4v xv[8];
#pragma unroll
      for (int j = 0; j < 8; ++j) xv[j] = *(const f32x4v*)(xr + k + 4 * j);
#pragma unroll
      for (int j = 0; j < 8; ++j) {
        f32x4v wv = *(const f32x4v*)(wc + k + 4 * j);
        a0 += (double)xv[j].x * (double)wv.x;
        a1 += (double)xv[j].y * (double)wv.y;
        a2 += (double)xv[j].z * (double)wv.z;
        a3 += (double)xv[j].w * (double)wv.w;
      }
    }
    logits_s[tok][e] = (float)(((a0 + a1) + (a2 + a3)) + (double)bcomb[e]);
  }
  __syncthreads();

  // ---- softmax / argmax / block-local counting sort ----
  if (t < BM) {
    float l0 = logits_s[t][0], l1 = logits_s[t][1];
    float l2 = logits_s[t][2], l3 = logits_s[t][3];
    float m = fmaxf(fmaxf(l0, l1), fmaxf(l2, l3));
    float s = __expf(l0 - m) + __expf(l1 - m) + __expf(l2 - m) + __expf(l3 - m);
    int e = 0; float bl = l0;
    if (l1 > bl) { bl = l1; e = 1; }
    if (l2 > bl) { bl = l2; e = 2; }
    if (l3 > bl) { bl = l3; e = 3; }
    gate_s[t] = 1.0f / s;
    eidx_s[t] = e;
    pos_s[t]  = atomicAdd(&cnt_s[e], 1);
  }
  __syncthreads();
  if (t == 0) {
    int b = 0;
#pragma unroll
    for (int e = 0; e < 4; ++e) { base_s[e] = b; b += cnt_s[e]; }
  }
  __syncthreads();
  if (t < BM) perm_s[base_s[eidx_s[t]] + pos_s[t]] = t;
  // (visible after the post-hs barrier below)

  // ---- stage 1: h = x @ W1, B direct from global (L2-hot), 8x2 wave split ----
  // wave w: rows [ (w>>1)*32, +32 ), cols [ (w&1)*128, +128 )
  const int rw = w >> 1, wc2 = w & 1;
  facc acc1[2][8];
#pragma unroll
  for (int m = 0; m < 2; ++m)
#pragma unroll
    for (int nt = 0; nt < 8; ++nt) acc1[m][nt] = (facc){0.f, 0.f, 0.f, 0.f};

  const float* xrow0 = x + (size_t)(tokbase + rw * 32 + cl) * HD;
  const float* xrow1 = xrow0 + 16 * HD;

#pragma unroll
  for (int kc = 0; kc < 4; ++kc) {
#pragma unroll
    for (int h2 = 0; h2 < 2; ++h2) {
      const int k0 = kc * 64 + h2 * 32 + q * 8;
      f32x4v xa0 = *(const f32x4v*)(xrow0 + k0);
      f32x4v xb0 = *(const f32x4v*)(xrow0 + k0 + 4);
      f32x4v xa1 = *(const f32x4v*)(xrow1 + k0);
      f32x4v xb1 = *(const f32x4v*)(xrow1 + k0 + 4);
      bfrag a0, a1;
      a0[0] = (short)f2bf(xa0.x); a0[1] = (short)f2bf(xa0.y);
      a0[2] = (short)f2bf(xa0.z); a0[3] = (short)f2bf(xa0.w);
      a0[4] = (short)f2bf(xb0.x); a0[5] = (short)f2bf(xb0.y);
      a0[6] = (short)f2bf(xb0.z); a0[7] = (short)f2bf(xb0.w);
      a1[0] = (short)f2bf(xa1.x); a1[1] = (short)f2bf(xa1.y);
      a1[2] = (short)f2bf(xa1.z); a1[3] = (short)f2bf(xa1.w);
      a1[4] = (short)f2bf(xb1.x); a1[5] = (short)f2bf(xb1.y);
      a1[6] = (short)f2bf(xb1.z); a1[7] = (short)f2bf(xb1.w);
      const u16* bp = w1t + (size_t)(kc * 2 + h2) * 8192
                          + (size_t)(wc2 * 8) * 512 + (cl * 4 + q) * 8;
#pragma unroll
      for (int nt = 0; nt < 8; ++nt) {
        bfrag bfr = *(const bfrag*)(bp + nt * 512);
        acc1[0][nt] = __builtin_amdgcn_mfma_f32_16x16x32_bf16(a0, bfr, acc1[0][nt], 0, 0, 0);
        acc1[1][nt] = __builtin_amdgcn_mfma_f32_16x16x32_bf16(a1, bfr, acc1[1][nt], 0, 0, 0);
      }
    }
  }
  // write h (+b1) to LDS as bf16
#pragma unroll
  for (int m = 0; m < 2; ++m)
#pragma unroll
    for (int nt = 0; nt < 8; ++nt) {
      const int c = wc2 * 128 + nt * 16 + cl;
      const float bb = b1s[c];
#pragma unroll
      for (int r = 0; r < 4; ++r)
        hs[rw * 32 + m * 16 + q * 4 + r][c] = f2bf(acc1[m][nt][r] + bb);
    }
  __syncthreads();

  // ---- stage 2: per-expert GEMM, B direct from global, 16 cols per wave ----
  const u16* wbase = wet + (size_t)w * 512 + (size_t)(cl * 4 + q) * 8;
  for (int e = 0; e < 4; ++e) {
    const int cnt = cnt_s[e];              // block-uniform
    const int ng   = (cnt + 15) >> 4;      // <= 16
    const int base = base_s[e];

    int  prow_r[16];
    bool val_r[16];
#pragma unroll
    for (int g = 0; g < 16; ++g) {
      const int rowi = g * 16 + cl;
      const bool v = rowi < cnt;
      val_r[g]  = v;
      prow_r[g] = perm_s[base + (v ? rowi : 0)];
    }

    facc acc2[16];
#pragma unroll
    for (int g = 0; g < 16; ++g) acc2[g] = (facc){0.f, 0.f, 0.f, 0.f};

    // one-step-ahead wf prefetch: next step's L2 load flies during this step's MFMAs
    bfrag wfc = *(const bfrag*)(wbase + (size_t)(e * 8) * 8192);
#pragma unroll
    for (int s = 0; s < 8; ++s) {
      const int k0 = s * 32 + q * 8;
      bfrag wf = wfc;
      if (s < 7) wfc = *(const bfrag*)(wbase + (size_t)(e * 8 + s + 1) * 8192);
#pragma unroll
      for (int g = 0; g < 16; ++g) {
        if (g < ng) {
          bfrag a = *(const bfrag*)&hs[prow_r[g]][k0];
          if (!val_r[g]) { bfrag z = {0,0,0,0,0,0,0,0}; a = z; }
          acc2[g] = __builtin_amdgcn_mfma_f32_16x16x32_bf16(a, wf, acc2[g], 0, 0, 0);
        }
      }
    }
    // epilogue: out = gate * (acc + be[e])
    {
      const int c = w * 16 + cl;
      const float bev = be[e * 256 + c];
#pragma unroll
      for (int g = 0; g < 16; ++g) {
        if (g < ng) {
#pragma unroll
          for (int r = 0; r < 4; ++r) {
            const int rowi = g * 16 + q * 4 + r;
            if (rowi < cnt) {
              const int tok = perm_s[base + rowi];
              out[(size_t)(tokbase + tok) * HD + c] = gate_s[tok] * (acc2[g][r] + bev);
            }
          }
        }
      }
    }
  }
}

extern "C" void kernel_launch(void* const* d_in, const int* in_sizes, int n_in,
                              void* d_out, int out_size, void* d_ws, size_t ws_size,
                              hipStream_t stream) {
  const float* x  = (const float*)d_in[0];
  const float* W1 = (const float*)d_in[1];
  const float* b1 = (const float*)d_in[2];
  const float* Wg = (const float*)d_in[3];
  const float* We = (const float*)d_in[4];
  const float* be = (const float*)d_in[5];
  float* out = (float*)d_out;

  char* ws = (char*)d_ws;
  u16*   w1t   = (u16*)(ws + WS_W1T);
  u16*   wet   = (u16*)(ws + WS_WET);
  float* wcomb = (float*)(ws + WS_WCOMB);
  float* bcomb = (float*)(ws + WS_BCOMB);
  unsigned long long* flag = (unsigned long long*)(ws + WS_FLAG);

  prep_all<<<417, 256, 0, stream>>>(W1, b1, Wg, We, w1t, wet, wcomb, bcomb, flag);
  moe_fused<<<NBLK, 1024, 0, stream>>>(x, w1t, wet, wcomb, bcomb, b1, be, out, flag);
}